// Round 7
// baseline (135.503 us; speedup 1.0000x reference)
//
#include <hip/hip_runtime.h>
#include <hip/hip_bf16.h>

typedef __attribute__((ext_vector_type(4)))  float          f32x4;
typedef __attribute__((ext_vector_type(8)))  short          bf16x8;
typedef __attribute__((ext_vector_type(8)))  unsigned short u16x8;
typedef __attribute__((ext_vector_type(4)))  unsigned int   u32x4;

#define Cc 512
#define Vv 512
#define BM 64
#define NTILE 2500

// Pre-swizzled bf16 W (16x16x32-MFMA B-fragment order) + f32 tanh of enc/pred.
__device__ unsigned short g_W2[Vv * Cc];
__device__ float g_ta[1600 * Cc];
__device__ float g_tp[400 * Cc];

__device__ __forceinline__ unsigned short f2bf(float f) {
    unsigned u = __float_as_uint(f);
    unsigned r = 0x7FFFu + ((u >> 16) & 1u);
    return (unsigned short)((u + r) >> 16);
}

__device__ __forceinline__ float fast_tanh(float x) {
    float e = __expf(2.0f * x);
    return 1.0f - 2.0f * __builtin_amdgcn_rcpf(e + 1.0f);
}

__device__ __forceinline__ unsigned cvt_pk_bf16(float lo, float hi) {
    unsigned r;
    asm("v_cvt_pk_bf16_f32 %0, %1, %2" : "=v"(r) : "v"(lo), "v"(hi));
    return r;
}

// blocks [0,128) -> W2 swizzle; [128,528) -> tanh(enc); [528,628) -> tanh(pred)
__global__ __launch_bounds__(256) void prep_kernel(
    const float* __restrict__ W, const float* __restrict__ enc,
    const float* __restrict__ pred)
{
    const int b = blockIdx.x;
    if (b < 128) {
        int gid = b * 256 + threadIdx.x;
        int v = gid >> 6;
        int k = (gid & 63) * 8;
        f32x4 a = *(const f32x4*)(W + v * Cc + k);
        f32x4 c = *(const f32x4*)(W + v * Cc + k + 4);
        u16x8 o;
#pragma unroll
        for (int j = 0; j < 4; ++j) {
            o[j]     = f2bf(a[j]);
            o[4 + j] = f2bf(c[j]);
        }
        int frag = (v >> 4) * 16 + (k >> 5);
        int lane = (v & 15) + 16 * ((k >> 3) & 3);
        *(u16x8*)(&g_W2[frag * 512 + lane * 8]) = o;
    } else if (b < 528) {
        int gid = (b - 128) * 256 + threadIdx.x;
        f32x4 a = *(const f32x4*)(enc + gid * 8);
        f32x4 c = *(const f32x4*)(enc + gid * 8 + 4);
        f32x4 o0, o1;
#pragma unroll
        for (int j = 0; j < 4; ++j) { o0[j] = fast_tanh(a[j]); o1[j] = fast_tanh(c[j]); }
        *(f32x4*)(g_ta + gid * 8)     = o0;
        *(f32x4*)(g_ta + gid * 8 + 4) = o1;
    } else {
        int gid = (b - 528) * 256 + threadIdx.x;
        f32x4 a = *(const f32x4*)(pred + gid * 8);
        f32x4 c = *(const f32x4*)(pred + gid * 8 + 4);
        f32x4 o0, o1;
#pragma unroll
        for (int j = 0; j < 4; ++j) { o0[j] = fast_tanh(a[j]); o1[j] = fast_tanh(c[j]); }
        *(f32x4*)(g_tp + gid * 8)     = o0;
        *(f32x4*)(g_tp + gid * 8 + 4) = o1;
    }
}

__global__ __launch_bounds__(512, 4) void joiner_main(
    const float* __restrict__ bias,  // (512,)
    float* __restrict__ out)         // (160000, 512)
{
    __shared__ unsigned short As[BM * Cc];   // 64 KB, XOR-swizzled rows

    const int tid = threadIdx.x;

    // ---- bijective XCD-chunked tile remap (8 XCDs, 2500 tiles; q=312,r=4) ----
    const int xcd  = blockIdx.x & 7;
    const int idx  = blockIdx.x >> 3;
    const int tile = (xcd < 4 ? xcd * 313 : 4 * 313 + (xcd - 4) * 312) + idx;

    // ---- stage: A = tanh(enc+pred) via tanh-sum identity -> bf16 LDS ----
    {
        const int r = tid >> 3;          // 0..63 (tile row)
        const int q = tid & 7;           // k-interleave slot
        const int m  = tile * BM + r;
        const int et = m / 100;
        const int u  = m - et * 100;
        const int bb = m / 40000;
        const int pr = bb * 100 + u;
        const float* taP = g_ta + et * Cc;
        const float* tpP = g_tp + pr * Cc;
        char* asB = (char*)As;
        const int swz = (r & 7) << 4;
#pragma unroll
        for (int c = 0; c < 8; ++c) {
            const int k0 = q * 8 + c * 64;      // interleaved chunks: bank-spread
            f32x4 a0 = *(const f32x4*)(taP + k0);
            f32x4 a1 = *(const f32x4*)(taP + k0 + 4);
            f32x4 p0 = *(const f32x4*)(tpP + k0);
            f32x4 p1 = *(const f32x4*)(tpP + k0 + 4);
            float rr[8];
#pragma unroll
            for (int j = 0; j < 4; ++j) {
                rr[j]     = (a0[j] + p0[j]) *
                            __builtin_amdgcn_rcpf(__builtin_fmaf(a0[j], p0[j], 1.0f));
                rr[4 + j] = (a1[j] + p1[j]) *
                            __builtin_amdgcn_rcpf(__builtin_fmaf(a1[j], p1[j], 1.0f));
            }
            u32x4 o;
#pragma unroll
            for (int j = 0; j < 4; ++j)
                o[j] = cvt_pk_bf16(rr[2 * j], rr[2 * j + 1]);
            int byte = r * 1024 + k0 * 2;
            *(u32x4*)(asB + (byte ^ swz)) = o;
        }
    }

    // ---- compute setup; first B-fragment issued BEFORE the barrier ----
    const int lane = tid & 63;
    const int w    = tid >> 6;          // wave -> V slice [w*64, (w+1)*64)
    const int lc   = lane & 15;
    const int lkB  = (lane >> 4) << 4;
    const int lr   = (lane >> 4) << 2;

    // flattened B-fragment stream: t = j*16 + ks, frag (w*64 + t), 1KB each
    const unsigned short* wb = &g_W2[(w * 64) * 512] + lane * 8;

    bf16x8 bcur, bnx;
    bcur = *(const bf16x8*)(wb);

    __syncthreads();   // only barrier

    const char* asB = (const char*)As;
    const int aswz = (lc & 7) << 4;

    for (int j = 0; j < 4; ++j) {
        f32x4 acc[4];
#pragma unroll
        for (int i = 0; i < 4; ++i) acc[i] = (f32x4){0.f, 0.f, 0.f, 0.f};

#pragma unroll 4
        for (int ks = 0; ks < 16; ++ks) {
            const int t = j * 16 + ks;
            if (t < 63) bnx = *(const bf16x8*)(wb + ((t + 1) << 9));
            bf16x8 af[4];
#pragma unroll
            for (int i = 0; i < 4; ++i) {
                int byte = (i * 16 + lc) * 1024 + ks * 64 + lkB;
                af[i] = *(const bf16x8*)(asB + (byte ^ aswz));
            }
#pragma unroll
            for (int i = 0; i < 4; ++i)
                acc[i] = __builtin_amdgcn_mfma_f32_16x16x32_bf16(
                    af[i], bcur, acc[i], 0, 0, 0);
            bcur = bnx;
        }

        // stream this V-fragment out now (stores overlap next j's MFMAs)
        const float bia = bias[w * 64 + j * 16 + lc];
#pragma unroll
        for (int i = 0; i < 4; ++i) {
#pragma unroll
            for (int q = 0; q < 4; ++q) {
                int row = tile * BM + i * 16 + lr + q;
                __builtin_nontemporal_store(acc[i][q] + bia,
                                            out + row * Vv + w * 64 + j * 16 + lc);
            }
        }
    }
}

extern "C" void kernel_launch(void* const* d_in, const int* in_sizes, int n_in,
                              void* d_out, int out_size, void* d_ws, size_t ws_size,
                              hipStream_t stream) {
    const float* enc  = (const float*)d_in[0];
    const float* pred = (const float*)d_in[1];
    const float* W    = (const float*)d_in[2];
    const float* bias = (const float*)d_in[3];
    float* out        = (float*)d_out;

    prep_kernel<<<628, 256, 0, stream>>>(W, enc, pred);
    joiner_main<<<NTILE, 512, 0, stream>>>(bias, out);
}

// Round 8
// 131.434 us; speedup vs baseline: 1.0310x; 1.0310x over previous
//
#include <hip/hip_runtime.h>
#include <hip/hip_bf16.h>

typedef __attribute__((ext_vector_type(2))) float          f32x2;
typedef __attribute__((ext_vector_type(4))) float          f32x4;
typedef __attribute__((ext_vector_type(8))) short          bf16x8;
typedef __attribute__((ext_vector_type(8))) unsigned short u16x8;
typedef __attribute__((ext_vector_type(4))) unsigned int   u32x4;

#define Cc 512
#define Vv 512
#define BM 64
#define KH 256
#define TPB 10
#define GRID 250   // 250 blocks x 10 tiles = 2500 tiles of 64 rows

// Pre-swizzled bf16 W (16x16x32 B-fragment order) + f32 tanh of enc/pred rows.
__device__ unsigned short g_W2[Vv * Cc];
__device__ float g_ta[1600 * Cc];
__device__ float g_tp[400 * Cc];

__device__ __forceinline__ unsigned short f2bf(float f) {
    unsigned u = __float_as_uint(f);
    unsigned r = 0x7FFFu + ((u >> 16) & 1u);
    return (unsigned short)((u + r) >> 16);
}

__device__ __forceinline__ float fast_tanh(float x) {
    float e = __expf(2.0f * x);
    return 1.0f - 2.0f * __builtin_amdgcn_rcpf(e + 1.0f);
}

__device__ __forceinline__ unsigned cvt_pk_bf16(float lo, float hi) {
    unsigned r;
    asm("v_cvt_pk_bf16_f32 %0, %1, %2" : "=v"(r) : "v"(lo), "v"(hi));
    return r;
}

// blocks [0,128) -> W2 swizzle; [128,528) -> tanh(enc); [528,628) -> tanh(pred)
__global__ __launch_bounds__(256) void prep_kernel(
    const float* __restrict__ W, const float* __restrict__ enc,
    const float* __restrict__ pred)
{
    const int b = blockIdx.x;
    if (b < 128) {
        int gid = b * 256 + threadIdx.x;
        int v = gid >> 6;
        int k = (gid & 63) * 8;
        f32x4 a = *(const f32x4*)(W + v * Cc + k);
        f32x4 c = *(const f32x4*)(W + v * Cc + k + 4);
        u16x8 o;
#pragma unroll
        for (int j = 0; j < 4; ++j) {
            o[j]     = f2bf(a[j]);
            o[4 + j] = f2bf(c[j]);
        }
        int frag = (v >> 4) * 16 + (k >> 5);
        int lane = (v & 15) + 16 * ((k >> 3) & 3);
        *(u16x8*)(&g_W2[frag * 512 + lane * 8]) = o;
    } else if (b < 528) {
        int gid = (b - 128) * 256 + threadIdx.x;
        f32x4 a = *(const f32x4*)(enc + gid * 8);
        f32x4 c = *(const f32x4*)(enc + gid * 8 + 4);
        f32x4 o0, o1;
#pragma unroll
        for (int j = 0; j < 4; ++j) { o0[j] = fast_tanh(a[j]); o1[j] = fast_tanh(c[j]); }
        *(f32x4*)(g_ta + gid * 8)     = o0;
        *(f32x4*)(g_ta + gid * 8 + 4) = o1;
    } else {
        int gid = (b - 528) * 256 + threadIdx.x;
        f32x4 a = *(const f32x4*)(pred + gid * 8);
        f32x4 c = *(const f32x4*)(pred + gid * 8 + 4);
        f32x4 o0, o1;
#pragma unroll
        for (int j = 0; j < 4; ++j) { o0[j] = fast_tanh(a[j]); o1[j] = fast_tanh(c[j]); }
        *(f32x4*)(g_tp + gid * 8)     = o0;
        *(f32x4*)(g_tp + gid * 8 + 4) = o1;
    }
}

__global__ __launch_bounds__(1024, 4) void joiner_main(
    const float* __restrict__ bias,  // (512,)
    float* __restrict__ out)         // (160000, 512)
{
    __shared__ unsigned short As[2][BM * KH];   // 2 x 32 KB half-K buffers

    const int tid  = threadIdx.x;
    const int lane = tid & 63;
    const int w    = tid >> 6;          // 0..15 -> V slice [w*32, w*32+32)
    const int lc   = lane & 15;
    const int lkB  = (lane >> 4) << 4;
    const int lr   = (lane >> 4) << 2;

    const int sr   = tid >> 4;          // stage row 0..63
    const int sq   = tid & 15;          // stage k-slot
    const int swzS = (sr & 7) << 4;
    const int aswz = (lc & 7) << 4;

    const int t0 = blockIdx.x * TPB;

    // wave's W2 window: cols [w*32, w*32+32); frag(cj,kf) at +(cj*16+kf)*1024B
    const char* wbL = (const char*)&g_W2[0] + (size_t)w * 32768 + lane * 16;

    const float bia0 = bias[w * 32 + lc];
    const float bia1 = bias[w * 32 + 16 + lc];

    // ---------- prologue: stage (t0, half0) -> buf0; init B ring ----------
    {
        int m  = t0 * BM + sr;
        int et = m / 100; int u = m - et * 100;
        int bb = m / 40000; int pr = bb * 100 + u;
        const float* taP = g_ta + et * Cc + sq * 8;
        const float* tpP = g_tp + pr * Cc + sq * 8;
        char* dst = (char*)&As[0][0];
#pragma unroll
        for (int c = 0; c < 2; ++c) {
            f32x4 a0 = *(const f32x4*)(taP + c * 128);
            f32x4 a1 = *(const f32x4*)(taP + c * 128 + 4);
            f32x4 p0 = *(const f32x4*)(tpP + c * 128);
            f32x4 p1 = *(const f32x4*)(tpP + c * 128 + 4);
            u32x4 o;
#pragma unroll
            for (int j = 0; j < 2; ++j) {
                float n0 = a0[2*j] + p0[2*j], d0 = __builtin_fmaf(a0[2*j], p0[2*j], 1.0f);
                float n1 = a0[2*j+1] + p0[2*j+1], d1 = __builtin_fmaf(a0[2*j+1], p0[2*j+1], 1.0f);
                o[j] = cvt_pk_bf16(n0 * __builtin_amdgcn_rcpf(d0),
                                   n1 * __builtin_amdgcn_rcpf(d1));
                float m0 = a1[2*j] + p1[2*j], e0 = __builtin_fmaf(a1[2*j], p1[2*j], 1.0f);
                float m1 = a1[2*j+1] + p1[2*j+1], e1 = __builtin_fmaf(a1[2*j+1], p1[2*j+1], 1.0f);
                o[2+j] = cvt_pk_bf16(m0 * __builtin_amdgcn_rcpf(e0),
                                     m1 * __builtin_amdgcn_rcpf(e1));
            }
            int byte = sr * 512 + sq * 16 + c * 256;
            *(u32x4*)(dst + (byte ^ swzS)) = o;
        }
    }

    bf16x8 b0[2], b1[2];                // period-2 B ring (frags kf, kf+1)
#pragma unroll
    for (int cj = 0; cj < 2; ++cj) {
        b0[cj] = *(const bf16x8*)(wbL + (cj * 16 + 0) * 1024);
        b1[cj] = *(const bf16x8*)(wbL + (cj * 16 + 1) * 1024);
    }

    f32x4 acc[4][2];
#pragma unroll
    for (int i = 0; i < 4; ++i) { acc[i][0] = (f32x4){0,0,0,0}; acc[i][1] = (f32x4){0,0,0,0}; }

    __syncthreads();

    // ---------- main loop: 20 halves (10 tiles), one barrier per half ----------
    for (int gh = 0; gh < 20; ++gh) {
        const int  base    = (gh & 1) * 8;
        const bool doStage = (gh < 19);

        // stage addressing for half gh+1
        const float* taP = g_ta;
        const float* tpP = g_tp;
        char* dstS = (char*)&As[(gh + 1) & 1][0];
        if (doStage) {
            int gn = gh + 1;
            int m  = (t0 + (gn >> 1)) * BM + sr;
            int et = m / 100; int u = m - et * 100;
            int bb = m / 40000; int pr = bb * 100 + u;
            taP = g_ta + et * Cc + (gn & 1) * KH + sq * 8;
            tpP = g_tp + pr * Cc + (gn & 1) * KH + sq * 8;
        }
        f32x2 aL[4], pL[4];             // stage ring, 3 ahead
        if (doStage) {
#pragma unroll
            for (int p = 0; p < 3; ++p) {
                aL[p] = *(const f32x2*)(taP + (p >> 2) * 128 + (p & 3) * 2);
                pL[p] = *(const f32x2*)(tpP + (p >> 2) * 128 + (p & 3) * 2);
            }
        }
        const char* src = (const char*)&As[gh & 1][0];

#pragma unroll
        for (int ks = 0; ks < 8; ++ks) {
            bf16x8 af[4];
#pragma unroll
            for (int i = 0; i < 4; ++i) {
                int byte = (i * 16 + lc) * 512 + ks * 64 + lkB;
                af[i] = *(const bf16x8*)(src + (byte ^ aswz));
            }
            if ((ks & 1) == 0) {
#pragma unroll
                for (int i = 0; i < 4; ++i) {
                    acc[i][0] = __builtin_amdgcn_mfma_f32_16x16x32_bf16(af[i], b0[0], acc[i][0], 0, 0, 0);
                    acc[i][1] = __builtin_amdgcn_mfma_f32_16x16x32_bf16(af[i], b0[1], acc[i][1], 0, 0, 0);
                }
            } else {
#pragma unroll
                for (int i = 0; i < 4; ++i) {
                    acc[i][0] = __builtin_amdgcn_mfma_f32_16x16x32_bf16(af[i], b1[0], acc[i][0], 0, 0, 0);
                    acc[i][1] = __builtin_amdgcn_mfma_f32_16x16x32_bf16(af[i], b1[1], acc[i][1], 0, 0, 0);
                }
            }
            // reload just-used ring slot with frag (base+ks+2) mod 16 (period-16 stream)
            {
                int kf = (base + ks + 2) & 15;
                if ((ks & 1) == 0) {
                    b0[0] = *(const bf16x8*)(wbL + (kf) * 1024);
                    b0[1] = *(const bf16x8*)(wbL + (16 + kf) * 1024);
                } else {
                    b1[0] = *(const bf16x8*)(wbL + (kf) * 1024);
                    b1[1] = *(const bf16x8*)(wbL + (16 + kf) * 1024);
                }
            }
            if (doStage) {
                if (ks < 5) {           // issue pair ks+3 (slot distinct from ks&3)
                    int p = ks + 3;
                    aL[p & 3] = *(const f32x2*)(taP + (p >> 2) * 128 + (p & 3) * 2);
                    pL[p & 3] = *(const f32x2*)(tpP + (p >> 2) * 128 + (p & 3) * 2);
                }
                // convert + write pair ks into next buffer
                f32x2 a = aL[ks & 3], pp = pL[ks & 3];
                float n0 = a[0] + pp[0], d0 = __builtin_fmaf(a[0], pp[0], 1.0f);
                float n1 = a[1] + pp[1], d1 = __builtin_fmaf(a[1], pp[1], 1.0f);
                unsigned o = cvt_pk_bf16(n0 * __builtin_amdgcn_rcpf(d0),
                                         n1 * __builtin_amdgcn_rcpf(d1));
                int byte = sr * 512 + sq * 16 + (ks >> 2) * 256 + (ks & 3) * 4;
                *(unsigned*)(dstS + (byte ^ swzS)) = o;
            }
        }

        if (gh & 1) {                   // tile finished: stream stores, reset acc
            int tC = t0 + (gh >> 1);
#pragma unroll
            for (int i = 0; i < 4; ++i) {
#pragma unroll
                for (int q = 0; q < 4; ++q) {
                    size_t row = (size_t)(tC * BM + i * 16 + lr + q);
                    float* op = out + row * Vv + w * 32 + lc;
                    __builtin_nontemporal_store(acc[i][0][q] + bia0, op);
                    __builtin_nontemporal_store(acc[i][1][q] + bia1, op + 16);
                }
                acc[i][0] = (f32x4){0,0,0,0};
                acc[i][1] = (f32x4){0,0,0,0};
            }
        }

        // barrier: LDS writes visible; do NOT drain vmcnt (stores stay in flight)
        asm volatile("s_waitcnt lgkmcnt(0)" ::: "memory");
        __builtin_amdgcn_s_barrier();
    }
}

extern "C" void kernel_launch(void* const* d_in, const int* in_sizes, int n_in,
                              void* d_out, int out_size, void* d_ws, size_t ws_size,
                              hipStream_t stream) {
    const float* enc  = (const float*)d_in[0];
    const float* pred = (const float*)d_in[1];
    const float* W    = (const float*)d_in[2];
    const float* bias = (const float*)d_in[3];
    float* out        = (float*)d_out;

    prep_kernel<<<628, 256, 0, stream>>>(W, enc, pred);
    joiner_main<<<GRID, 1024, 0, stream>>>(bias, out);
}